// Round 1
// baseline (932.175 us; speedup 1.0000x reference)
//
#include <hip/hip_runtime.h>

typedef unsigned short u16;
typedef unsigned int u32;
typedef __attribute__((ext_vector_type(8))) short short8;
typedef __attribute__((ext_vector_type(4))) float floatx4;

#define MFMA16(A,B,C) __builtin_amdgcn_mfma_f32_16x16x32_bf16((A),(B),(C),0,0,0)

// B=4, T=1024, H=16, D=64; BH=64; rows (b,t,h) = 65536 per side.
// out[0] = true softmax map, out[1] = pred map; each B*T*H*T = 67108864 f32.

__device__ __forceinline__ u16 f2bf(float f){
  u32 u = __float_as_uint(f);
  u32 r = (u + 0x7fffu + ((u >> 16) & 1u)) >> 16;
  return (u16)r;
}
__device__ __forceinline__ float bf2f(u16 h){
  return __uint_as_float(((u32)h) << 16);
}
__device__ __forceinline__ short8 ld8(const u16* p){
  return *(const short8*)p;
}

// ---------------- Kernel A: feature map + bf16 hi/lo split ----------------
// 1 thread per (b,t,h) row; gid<65536 -> q, else k.
// Writes (layout [BH][T][...]): qh/ql (q/8 split, bf16 64), kh/kl (k split),
// phiq/phik (bf16 128 = [exp(y), exp(-y)]).
__global__ __launch_bounds__(256) void featmap_kernel(
    const float* __restrict__ q, const float* __restrict__ k,
    const float* __restrict__ Wq, const float* __restrict__ bq,
    const float* __restrict__ Wk, const float* __restrict__ bk,
    u16* __restrict__ qh, u16* __restrict__ ql,
    u16* __restrict__ kh, u16* __restrict__ kl,
    u16* __restrict__ phiq, u16* __restrict__ phik) {
  u32 gid = blockIdx.x * 256u + threadIdx.x;
  bool is_k = gid >= 65536u;
  u32 r = is_k ? (gid - 65536u) : gid;
  const float* __restrict__ x = (is_k ? k : q) + (size_t)r * 64u;
  const float* __restrict__ W = is_k ? Wk : Wq;
  const float* __restrict__ bias = is_k ? bk : bq;
  u32 b = r >> 14, t = (r >> 4) & 1023u, h = r & 15u;
  u32 orow = (b * 16u + h) * 1024u + t;

  float xv[64];
#pragma unroll
  for (int i = 0; i < 16; i++) {
    float4 v = ((const float4*)x)[i];
    xv[4 * i + 0] = v.x; xv[4 * i + 1] = v.y;
    xv[4 * i + 2] = v.z; xv[4 * i + 3] = v.w;
  }

  // split store (q gets the 1/sqrt(D)=1/8 scale folded in)
  float scale = is_k ? 1.0f : 0.125f;
  u16* hdst = (is_k ? kh : qh) + (size_t)orow * 64u;
  u16* ldst = (is_k ? kl : ql) + (size_t)orow * 64u;
#pragma unroll
  for (int c = 0; c < 8; c++) {
    u16 hi[8] __attribute__((aligned(16)));
    u16 lo[8] __attribute__((aligned(16)));
#pragma unroll
    for (int j = 0; j < 8; j++) {
      float xs = xv[c * 8 + j] * scale;
      u16 hb = f2bf(xs);
      hi[j] = hb;
      lo[j] = f2bf(xs - bf2f(hb));
    }
    ((uint4*)hdst)[c] = *(const uint4*)hi;
    ((uint4*)ldst)[c] = *(const uint4*)lo;
  }

  // y = x @ W^T + b ; phi = [exp(y), exp(-y)]
  u16* pdst = (is_k ? phik : phiq) + (size_t)orow * 128u;
#pragma unroll
  for (int c = 0; c < 4; c++) {
    float accs[16];
#pragma unroll
    for (int i = 0; i < 16; i++) accs[i] = bias[c * 16 + i];
#pragma unroll
    for (int d = 0; d < 64; d++) {
      float xd = xv[d];
#pragma unroll
      for (int i = 0; i < 16; i++) accs[i] += xd * W[(c * 16 + i) * 64 + d];
    }
    u16 pl[16] __attribute__((aligned(16)));
    u16 pm[16] __attribute__((aligned(16)));
#pragma unroll
    for (int i = 0; i < 16; i++) {
      pl[i] = f2bf(__expf(accs[i]));
      pm[i] = f2bf(__expf(-accs[i]));
    }
    ((uint4*)pdst)[2 * c + 0] = ((const uint4*)pl)[0];
    ((uint4*)pdst)[2 * c + 1] = ((const uint4*)pl)[1];
    ((uint4*)(pdst + 64))[2 * c + 0] = ((const uint4*)pm)[0];
    ((uint4*)(pdst + 64))[2 * c + 1] = ((const uint4*)pm)[1];
  }
}

// ---------------- Kernel B: column-sum of phik per (b,h) ----------------
__global__ __launch_bounds__(128) void colsum_kernel(
    const u16* __restrict__ phik, float* __restrict__ colsum) {
  int bh = blockIdx.x;
  int e = threadIdx.x; // 0..127
  const u16* p = phik + (size_t)bh * 1024u * 128u + e;
  float s = 0.f;
#pragma unroll 8
  for (int t = 0; t < 1024; t++) s += bf2f(p[(size_t)t * 128u]);
  colsum[bh * 128 + e] = s;
}

// ---------------- Kernel C: Z_true = sum_c exp(s) per query row ----------------
// block = (bh, 32-row strip); 4 waves split the 1024 key columns.
__global__ __launch_bounds__(256) void ztrue_kernel(
    const u16* __restrict__ qh, const u16* __restrict__ ql,
    const u16* __restrict__ kh, const u16* __restrict__ kl,
    float* __restrict__ ztrue) {
  int bh = blockIdx.x >> 5, strip = blockIdx.x & 31;
  int tid = threadIdx.x, w = tid >> 6, lane = tid & 63, quad = lane >> 4, n16 = lane & 15;
  u32 base = (u32)bh * 1024u;

  short8 aqh[2][2], aql[2][2];
#pragma unroll
  for (int m = 0; m < 2; m++) {
    u32 row = base + strip * 32u + m * 16u + n16;
#pragma unroll
    for (int ks = 0; ks < 2; ks++) {
      aqh[m][ks] = ld8(qh + (size_t)row * 64u + ks * 32u + quad * 8u);
      aql[m][ks] = ld8(ql + (size_t)row * 64u + ks * 32u + quad * 8u);
    }
  }

  float zp[2][4] = {{0.f,0.f,0.f,0.f},{0.f,0.f,0.f,0.f}};
  for (int ct = w * 16; ct < w * 16 + 16; ++ct) {
    u32 col = base + (u32)ct * 16u + n16;
    const u16* kp = kh + (size_t)col * 64u + quad * 8u;
    const u16* lp = kl + (size_t)col * 64u + quad * 8u;
    short8 b0 = ld8(kp), b1 = ld8(kp + 32), c0 = ld8(lp), c1 = ld8(lp + 32);
#pragma unroll
    for (int m = 0; m < 2; m++) {
      floatx4 acc = {0.f, 0.f, 0.f, 0.f};
      acc = MFMA16(aqh[m][0], b0, acc);
      acc = MFMA16(aqh[m][1], b1, acc);
      acc = MFMA16(aqh[m][0], c0, acc);
      acc = MFMA16(aqh[m][1], c1, acc);
      acc = MFMA16(aql[m][0], b0, acc);
      acc = MFMA16(aql[m][1], b1, acc);
#pragma unroll
      for (int r = 0; r < 4; r++) zp[m][r] += __expf(acc[r]);
    }
  }
#pragma unroll
  for (int m = 0; m < 2; m++)
#pragma unroll
    for (int r = 0; r < 4; r++)
#pragma unroll
      for (int off = 1; off < 16; off <<= 1)
        zp[m][r] += __shfl_xor(zp[m][r], off);

  __shared__ float zbuf[4][32];
  if (n16 == 0) {
#pragma unroll
    for (int m = 0; m < 2; m++)
#pragma unroll
      for (int r = 0; r < 4; r++)
        zbuf[w][m * 16 + quad * 4 + r] = zp[m][r];
  }
  __syncthreads();
  if (tid < 32)
    ztrue[base + strip * 32u + tid] =
        zbuf[0][tid] + zbuf[1][tid] + zbuf[2][tid] + zbuf[3][tid];
}

// ---------------- Kernel D: emit both normalized maps ----------------
__global__ __launch_bounds__(256) void emit_kernel(
    const u16* __restrict__ qh, const u16* __restrict__ ql,
    const u16* __restrict__ kh, const u16* __restrict__ kl,
    const u16* __restrict__ phiq, const u16* __restrict__ phik,
    const float* __restrict__ colsum, const float* __restrict__ ztrue,
    float* __restrict__ out) {
  int bh = blockIdx.x >> 5, strip = blockIdx.x & 31;
  int tid = threadIdx.x, w = tid >> 6, lane = tid & 63, quad = lane >> 4, n16 = lane & 15;
  u32 base = (u32)bh * 1024u;

  __shared__ float cs[128];
  __shared__ float rz[2][32]; // [0]=1/Ztrue, [1]=1/Zpred
  if (tid < 128) cs[tid] = colsum[bh * 128 + tid];
  __syncthreads();
  if (tid < 32) {
    u32 row = base + strip * 32u + tid;
    float zpd = 0.f;
#pragma unroll 8
    for (int j = 0; j < 128; j++) zpd += bf2f(phiq[(size_t)row * 128u + j]) * cs[j];
    rz[1][tid] = 1.f / zpd;
    rz[0][tid] = 1.f / ztrue[row];
  }

  short8 aqh[2][2], aql[2][2], apq[2][4];
#pragma unroll
  for (int m = 0; m < 2; m++) {
    u32 row = base + strip * 32u + m * 16u + n16;
#pragma unroll
    for (int ks = 0; ks < 2; ks++) {
      aqh[m][ks] = ld8(qh + (size_t)row * 64u + ks * 32u + quad * 8u);
      aql[m][ks] = ld8(ql + (size_t)row * 64u + ks * 32u + quad * 8u);
    }
#pragma unroll
    for (int ks = 0; ks < 4; ks++)
      apq[m][ks] = ld8(phiq + (size_t)row * 128u + ks * 32u + quad * 8u);
  }
  __syncthreads();

  float rzt[2][4], rzp[2][4];
  u32 tb[2][4];
  u32 bb = (u32)bh >> 4, hh = (u32)bh & 15u;
#pragma unroll
  for (int m = 0; m < 2; m++)
#pragma unroll
    for (int r = 0; r < 4; r++) {
      int rr = m * 16 + quad * 4 + r;
      rzt[m][r] = rz[0][rr];
      rzp[m][r] = rz[1][rr];
      u32 t = strip * 32u + rr;
      tb[m][r] = ((bb * 1024u + t) * 16u + hh) * 1024u;
    }

  for (int ct = w * 16; ct < w * 16 + 16; ++ct) {
    u32 col = base + (u32)ct * 16u + n16;
    const u16* kp = kh + (size_t)col * 64u + quad * 8u;
    const u16* lp = kl + (size_t)col * 64u + quad * 8u;
    const u16* pp = phik + (size_t)col * 128u + quad * 8u;
    short8 b0 = ld8(kp), b1 = ld8(kp + 32), c0 = ld8(lp), c1 = ld8(lp + 32);
    short8 p0 = ld8(pp), p1 = ld8(pp + 32), p2 = ld8(pp + 64), p3 = ld8(pp + 96);
    u32 cidx = (u32)ct * 16u + n16;
#pragma unroll
    for (int m = 0; m < 2; m++) {
      floatx4 acc = {0.f, 0.f, 0.f, 0.f};
      acc = MFMA16(aqh[m][0], b0, acc);
      acc = MFMA16(aqh[m][1], b1, acc);
      acc = MFMA16(aqh[m][0], c0, acc);
      acc = MFMA16(aqh[m][1], c1, acc);
      acc = MFMA16(aql[m][0], b0, acc);
      acc = MFMA16(aql[m][1], b1, acc);
      floatx4 ap = {0.f, 0.f, 0.f, 0.f};
      ap = MFMA16(apq[m][0], p0, ap);
      ap = MFMA16(apq[m][1], p1, ap);
      ap = MFMA16(apq[m][2], p2, ap);
      ap = MFMA16(apq[m][3], p3, ap);
#pragma unroll
      for (int r = 0; r < 4; r++) {
        out[tb[m][r] + cidx] = __expf(acc[r]) * rzt[m][r];
        out[67108864u + tb[m][r] + cidx] = ap[r] * rzp[m][r];
      }
    }
  }
}

extern "C" void kernel_launch(void* const* d_in, const int* in_sizes, int n_in,
                              void* d_out, int out_size, void* d_ws, size_t ws_size,
                              hipStream_t stream) {
  const float* q  = (const float*)d_in[0];
  const float* k  = (const float*)d_in[1];
  const float* Wq = (const float*)d_in[2];
  const float* bq = (const float*)d_in[3];
  const float* Wk = (const float*)d_in[4];
  const float* bk = (const float*)d_in[5];
  unsigned char* ws = (unsigned char*)d_ws;
  // ws layout (bytes): qh 8M | ql 8M | kh 8M | kl 8M | phiq 16M | phik 16M |
  //                    colsum 32K | ztrue 256K   (total ~64.3 MB)
  u16* qh   = (u16*)(ws + (0ull  << 20));
  u16* ql   = (u16*)(ws + (8ull  << 20));
  u16* kh   = (u16*)(ws + (16ull << 20));
  u16* kl   = (u16*)(ws + (24ull << 20));
  u16* phiq = (u16*)(ws + (32ull << 20));
  u16* phik = (u16*)(ws + (48ull << 20));
  float* colsum = (float*)(ws + (64ull << 20));
  float* ztrue  = (float*)(ws + (64ull << 20) + 32768ull);
  float* out = (float*)d_out;

  hipLaunchKernelGGL(featmap_kernel, dim3(512), dim3(256), 0, stream,
                     q, k, Wq, bq, Wk, bk, qh, ql, kh, kl, phiq, phik);
  hipLaunchKernelGGL(colsum_kernel, dim3(64), dim3(128), 0, stream, phik, colsum);
  hipLaunchKernelGGL(ztrue_kernel, dim3(2048), dim3(256), 0, stream,
                     qh, ql, kh, kl, ztrue);
  hipLaunchKernelGGL(emit_kernel, dim3(2048), dim3(256), 0, stream,
                     qh, ql, kh, kl, phiq, phik, colsum, ztrue, out);
}